// Round 10
// baseline (393.154 us; speedup 1.0000x reference)
//
#include <hip/hip_runtime.h>
#include <hip/hip_cooperative_groups.h>
#include <math.h>

namespace cg = cooperative_groups;

#define WAVE 64

// Single cooperative kernel: the 1.074 GB zero-fill (BW-bound, ~165 us)
// overlaps the router preamble (softmax/top2/hist, ~10 us of work) instead
// of serializing behind it; grid.sync() then orders the sparse patch.
// Phase bodies are the verified R3-K1 (softmax+hist) and R9 (scan+rank+
// scatter) implementations.
__global__ void __launch_bounds__(256, 4)
fused_router(const float* __restrict__ x,
             float* __restrict__ out,
             int* __restrict__ top1,
             int* __restrict__ top2,
             float* __restrict__ w1,
             float* __restrict__ w2,
             int* __restrict__ hist1,
             int* __restrict__ hist2,
             int S, int CAP, int nchunks, int NB) {
    __shared__ int lh1[64], lh2[64];
    const int tid = threadIdx.x;

    // ---------------- Phase 1a: flat grid-stride zero-fill ----------------
    // Linear coalesced float4 stores over the full output (both tensors).
    {
        float4* out4 = (float4*)out;
        const size_t n4 = ((size_t)2 * S * 64 * CAP) >> 2;
        const size_t nthreads = (size_t)NB * 256;
        const float4 z = make_float4(0.0f, 0.0f, 0.0f, 0.0f);
        for (size_t i = (size_t)blockIdx.x * 256 + tid; i < n4; i += nthreads)
            out4[i] = z;
    }

    // ---------------- Phase 1b: softmax + top2 + chunk hist ---------------
    // Blocks 0..nchunks-1 only; runs concurrently with other blocks' fill.
    if (blockIdx.x < (unsigned)nchunks) {
        const int c    = blockIdx.x;
        const int wid  = tid >> 6;
        const int lane = tid & 63;

        if (tid < 64) { lh1[tid] = 0; lh2[tid] = 0; }
        __syncthreads();

        #pragma unroll 4
        for (int k = 0; k < 16; ++k) {
            const int s = c * 64 + wid * 16 + k;
            const float v = x[(size_t)s * 64 + lane];

            // argmax, lowest-index tiebreak (matches jnp.argmax)
            float bv = v; int bi = lane;
            #pragma unroll
            for (int off = 32; off >= 1; off >>= 1) {
                float ov = __shfl_xor(bv, off, WAVE);
                int   oi = __shfl_xor(bi, off, WAVE);
                if (ov > bv || (ov == bv && oi < bi)) { bv = ov; bi = oi; }
            }
            const float m = bv;
            const int t1 = bi;

            // fp32 softmax
            float e = expf(v - m);
            float sum = e;
            #pragma unroll
            for (int off = 32; off >= 1; off >>= 1) sum += __shfl_xor(sum, off, WAVE);
            const float p = e / sum;

            // second argmax with top1 masked out
            float v2 = (lane == t1) ? -INFINITY : v;
            float bv2 = v2; int bi2 = lane;
            #pragma unroll
            for (int off = 32; off >= 1; off >>= 1) {
                float ov = __shfl_xor(bv2, off, WAVE);
                int   oi = __shfl_xor(bi2, off, WAVE);
                if (ov > bv2 || (ov == bv2 && oi < bi2)) { bv2 = ov; bi2 = oi; }
            }
            const int t2 = bi2;

            const float p1 = __shfl(p, t1, WAVE);
            const float p2 = __shfl(p, t2, WAVE);

            if (lane == 0) {
                top1[s] = t1; top2[s] = t2;
                w1[s] = p1;   w2[s] = p2;
                atomicAdd(&lh1[t1], 1);
                atomicAdd(&lh2[t2], 1);
            }
        }
        __syncthreads();
        if (tid < 64) {
            hist1[c * 64 + tid] = lh1[tid];
            hist2[c * 64 + tid] = lh2[tid];
        }
    }

    // ---------------- grid-wide barrier (device-scope fence) --------------
    cg::this_grid().sync();

    // ---------------- Phase 2: scan + ranks + sparse scatter --------------
    // Wave 0 of blocks 0..nchunks-1 (R9's verified body).
    if (blockIdx.x < (unsigned)nchunks && tid < 64) {
        const int c = blockIdx.x;
        const int i = tid;
        const int s = c * 64 + i;

        // thread i = expert i: exclusive base over chunks + pre-drop totals
        int b1 = 0, b2 = 0, tot1 = 0;
        #pragma unroll 8
        for (int cc = 0; cc < nchunks; ++cc) {
            const int h1 = hist1[cc * 64 + i];
            const int h2 = hist2[cc * 64 + i];
            const int lt = (cc < c);
            b1   += lt ? h1 : 0;
            b2   += lt ? h2 : 0;
            tot1 += h1;
        }

        const int t1 = top1[s];
        const int t2 = top2[s];

        // within-chunk stable counts
        int cnt1 = 0, cnt2 = 0;
        #pragma unroll 8
        for (int j = 0; j < 64; ++j) {
            const int o1 = __shfl(t1, j, WAVE);
            const int o2 = __shfl(t2, j, WAVE);
            cnt1 += (o1 == t1) && (j < i);
            cnt2 += (o2 == t2) && (j < i);
        }

        const int rank1 = __shfl(b1, t1, WAVE) + cnt1;
        const int rank2 = __shfl(b2, t2, WAVE) + cnt2 + __shfl(tot1, t2, WAVE);

        const size_t secoff = (size_t)S * 64 * CAP;
        if (rank1 < CAP) {
            const size_t idx = ((size_t)s * 64 + t1) * CAP + rank1;
            out[idx] = w1[s];
            out[secoff + idx] = 1.0f;
        }
        if (rank2 < CAP) {
            const size_t idx = ((size_t)s * 64 + t2) * CAP + rank2;
            out[idx] = w2[s];
            out[secoff + idx] = 1.0f;
        }
    }
}

extern "C" void kernel_launch(void* const* d_in, const int* in_sizes, int n_in,
                              void* d_out, int out_size, void* d_ws, size_t ws_size,
                              hipStream_t stream) {
    const float* x = (const float*)d_in[0];
    float* out = (float*)d_out;

    const int E = 64;
    int S = in_sizes[0] / E;                  // 8192
    int cap = (int)(2.0 * S / E);
    cap += cap % 2;
    if (cap < 4) cap = 4;                     // 256
    int nchunks = S / 64;                     // 128

    // workspace layout
    char* w = (char*)d_ws;
    int*   top1  = (int*)w;   w += (size_t)S * 4;
    int*   top2  = (int*)w;   w += (size_t)S * 4;
    float* w1    = (float*)w; w += (size_t)S * 4;
    float* w2    = (float*)w; w += (size_t)S * 4;
    int*   hist1 = (int*)w;   w += (size_t)nchunks * 64 * 4;
    int*   hist2 = (int*)w;   w += (size_t)nchunks * 64 * 4;

    int NB = 1024;                            // 4 blocks/CU: co-resident
    if (NB < nchunks) NB = nchunks;

    void* args[] = { (void*)&x, (void*)&out,
                     (void*)&top1, (void*)&top2,
                     (void*)&w1, (void*)&w2,
                     (void*)&hist1, (void*)&hist2,
                     (void*)&S, (void*)&cap, (void*)&nchunks, (void*)&NB };

    hipLaunchCooperativeKernel((const void*)fused_router,
                               dim3(NB), dim3(256), args, 0, stream);
}

// Round 11
// 215.572 us; speedup vs baseline: 1.8238x; 1.8238x over previous
//
#include <hip/hip_runtime.h>
#include <hip/hip_bf16.h>
#include <math.h>

#define WAVE 64

// R9 champion (195 us) with ONE change: softmax+top2 and chunk_hist fused
// into a single kernel (R3's verified body). Dispatches 4 -> 3.
// Empirical laws: hipMemsetAsync is the only 6.5 TB/s filler; avoid
// sparse-grid ballot shapes; avoid serial scans; avoid cooperative launch.

// ---------------- K1: softmax + top1/top2 + per-chunk expert histogram ----
// One 256-thread block (4 waves) per 64-token chunk; each wave handles 16
// tokens serially, lane e = expert e. Histogram via LDS atomics (count sums
// are order-independent -> deterministic).
__global__ void __launch_bounds__(256)
softmax_top2_hist(const float* __restrict__ x,
                  int* __restrict__ top1,
                  int* __restrict__ top2,
                  float* __restrict__ w1,
                  float* __restrict__ w2,
                  int* __restrict__ hist1,
                  int* __restrict__ hist2) {
    __shared__ int lh1[64], lh2[64];
    const int c    = blockIdx.x;
    const int wid  = threadIdx.x >> 6;
    const int lane = threadIdx.x & 63;

    if (threadIdx.x < 64) { lh1[threadIdx.x] = 0; lh2[threadIdx.x] = 0; }
    __syncthreads();

    #pragma unroll 4
    for (int k = 0; k < 16; ++k) {
        const int s = c * 64 + wid * 16 + k;
        const float v = x[(size_t)s * 64 + lane];

        // argmax, lowest-index tiebreak (matches jnp.argmax)
        float bv = v; int bi = lane;
        #pragma unroll
        for (int off = 32; off >= 1; off >>= 1) {
            float ov = __shfl_xor(bv, off, WAVE);
            int   oi = __shfl_xor(bi, off, WAVE);
            if (ov > bv || (ov == bv && oi < bi)) { bv = ov; bi = oi; }
        }
        const float m = bv;
        const int t1 = bi;

        // fp32 softmax
        float e = expf(v - m);
        float sum = e;
        #pragma unroll
        for (int off = 32; off >= 1; off >>= 1) sum += __shfl_xor(sum, off, WAVE);
        const float p = e / sum;

        // second argmax with top1 masked out
        float v2 = (lane == t1) ? -INFINITY : v;
        float bv2 = v2; int bi2 = lane;
        #pragma unroll
        for (int off = 32; off >= 1; off >>= 1) {
            float ov = __shfl_xor(bv2, off, WAVE);
            int   oi = __shfl_xor(bi2, off, WAVE);
            if (ov > bv2 || (ov == bv2 && oi < bi2)) { bv2 = ov; bi2 = oi; }
        }
        const int t2 = bi2;

        const float p1 = __shfl(p, t1, WAVE);
        const float p2 = __shfl(p, t2, WAVE);

        if (lane == 0) {
            top1[s] = t1; top2[s] = t2;
            w1[s] = p1;   w2[s] = p2;
            atomicAdd(&lh1[t1], 1);
            atomicAdd(&lh2[t2], 1);
        }
    }
    __syncthreads();
    if (threadIdx.x < 64) {
        hist1[c * 64 + threadIdx.x] = lh1[threadIdx.x];
        hist2[c * 64 + threadIdx.x] = lh2[threadIdx.x];
    }
}

// ---------------- K2: fused scan + ranks + scatter (R9 verified) ----------
// One 64-lane block per chunk. Thread i = expert i for the scan phase:
// sweeps hist arrays (coalesced across the wave, loads independent ->
// pipelined), accumulating this chunk's exclusive base and the full
// pre-drop top-1 totals. Bases for each token's experts fetched via shfl.
__global__ void rank_scatter(const int* __restrict__ top1,
                             const int* __restrict__ top2,
                             const float* __restrict__ w1,
                             const float* __restrict__ w2,
                             const int* __restrict__ hist1,
                             const int* __restrict__ hist2,
                             float* __restrict__ out,
                             int S, int CAP, int nchunks) {
    const int c = blockIdx.x;
    const int i = threadIdx.x;
    const int s = c * 64 + i;

    // scan phase: thread i accumulates expert-i counts
    int b1 = 0, b2 = 0, tot1 = 0;
    #pragma unroll 8
    for (int cc = 0; cc < nchunks; ++cc) {
        const int h1 = hist1[cc * 64 + i];
        const int h2 = hist2[cc * 64 + i];
        const int lt = (cc < c);
        b1   += lt ? h1 : 0;
        b2   += lt ? h2 : 0;
        tot1 += h1;                 // full pre-drop top-1 count of expert i
    }

    const int t1 = top1[s];
    const int t2 = top2[s];

    // within-chunk stable counts
    int cnt1 = 0, cnt2 = 0;
    #pragma unroll 8
    for (int j = 0; j < 64; ++j) {
        const int o1 = __shfl(t1, j, WAVE);
        const int o2 = __shfl(t2, j, WAVE);
        cnt1 += (o1 == t1) && (j < i);
        cnt2 += (o2 == t2) && (j < i);
    }

    const int rank1 = __shfl(b1, t1, WAVE) + cnt1;
    const int rank2 = __shfl(b2, t2, WAVE) + cnt2 + __shfl(tot1, t2, WAVE);

    const size_t secoff = (size_t)S * 64 * CAP;
    if (rank1 < CAP) {
        const size_t idx = ((size_t)s * 64 + t1) * CAP + rank1;
        out[idx] = w1[s];
        out[secoff + idx] = 1.0f;
    }
    if (rank2 < CAP) {
        const size_t idx = ((size_t)s * 64 + t2) * CAP + rank2;
        out[idx] = w2[s];
        out[secoff + idx] = 1.0f;
    }
}

extern "C" void kernel_launch(void* const* d_in, const int* in_sizes, int n_in,
                              void* d_out, int out_size, void* d_ws, size_t ws_size,
                              hipStream_t stream) {
    const float* x = (const float*)d_in[0];
    float* out = (float*)d_out;

    const int E = 64;
    const int S = in_sizes[0] / E;            // 8192
    int cap = (int)(2.0 * S / E);
    cap += cap % 2;
    if (cap < 4) cap = 4;                     // 256

    const int nchunks = S / 64;               // 128

    // workspace layout (all 4-byte elements)
    char* w = (char*)d_ws;
    int*   top1   = (int*)w;   w += (size_t)S * 4;
    int*   top2   = (int*)w;   w += (size_t)S * 4;
    float* w1     = (float*)w; w += (size_t)S * 4;
    float* w2     = (float*)w; w += (size_t)S * 4;
    int*   hist1  = (int*)w;   w += (size_t)nchunks * 64 * 4;
    int*   hist2  = (int*)w;   w += (size_t)nchunks * 64 * 4;

    // 1) zero the dense output FIRST (champion ordering; 6.5 TB/s filler)
    hipMemsetAsync(d_out, 0, (size_t)out_size * sizeof(float), stream);

    // 2) fused softmax + top2 + per-chunk histogram (one block per chunk)
    softmax_top2_hist<<<nchunks, 256, 0, stream>>>(x, top1, top2, w1, w2,
                                                   hist1, hist2);

    // 3) fused scan + ranks + scatter
    rank_scatter<<<nchunks, 64, 0, stream>>>(top1, top2, w1, w2,
                                             hist1, hist2, out,
                                             S, cap, nchunks);
}